// Round 2
// baseline (108.116 us; speedup 1.0000x reference)
//
#include <hip/hip_runtime.h>

#define BS_TOTAL 256   // B*S
#define NP 64          // prototypes
#define NV 2562        // vertices
#define GROUP 4        // bs per main-kernel block
#define TB 128         // threads per main-kernel block (one v each)
#define RWS_STRIDE 12  // 9 used + 3 pad, keeps 16B alignment

// ---------------- prep: per (bs,p) scaled rotation matrix + reductions ------
__global__ __launch_bounds__(64) void prep_kernel(
    const float* __restrict__ scales,      // [256]
    const float* __restrict__ transforms,  // [256][64][6]
    const float* __restrict__ weights,     // [256][64]
    float* __restrict__ rws,               // [256][64][12]
    float* __restrict__ aux)               // [256][12]  (Rsum[9], trans[3])
{
    const int bs = blockIdx.x;
    const int p  = threadIdx.x;

    const float* t = transforms + ((size_t)bs * NP + p) * 6;
    const float tx = t[0], ty = t[1], tz = t[2];
    const float ax = t[3], ay = t[4], az = t[5];
    const float w  = weights[bs * NP + p];
    const float sc = scales[bs];
    const float ws = w * sc;

    float sx, cx, sy, cy, sz, cz;
    __sincosf(ax, &sx, &cx);
    __sincosf(ay, &sy, &cy);
    __sincosf(az, &sz, &cz);

    // R = Rx(ax) @ Ry(ay) @ Rz(az), row-major
    float v12[12];
    v12[0] = (cy * cz) * ws;
    v12[1] = (-cy * sz) * ws;
    v12[2] = (sy) * ws;
    v12[3] = (cx * sz + sx * sy * cz) * ws;
    v12[4] = (cx * cz - sx * sy * sz) * ws;
    v12[5] = (-sx * cy) * ws;
    v12[6] = (sx * sz - cx * sy * cz) * ws;
    v12[7] = (sx * cz + cx * sy * sz) * ws;
    v12[8] = (cx * cy) * ws;
    v12[9]  = w * tx;
    v12[10] = w * ty;
    v12[11] = w * tz;

    float4* dst = (float4*)(rws + ((size_t)bs * NP + p) * RWS_STRIDE);
    dst[0] = make_float4(v12[0], v12[1], v12[2],  v12[3]);
    dst[1] = make_float4(v12[4], v12[5], v12[6],  v12[7]);
    dst[2] = make_float4(v12[8], v12[9], v12[10], v12[11]);

    // wave(=block) reduction over p: Rsum (k=0..8), trans (k=9..11)
    float red[12];
#pragma unroll
    for (int k = 0; k < 12; ++k) red[k] = v12[k];
#pragma unroll
    for (int m = 1; m < 64; m <<= 1) {
#pragma unroll
        for (int k = 0; k < 12; ++k) red[k] += __shfl_xor(red[k], m);
    }
    if (p == 0) {
        float4* adst = (float4*)(aux + (size_t)bs * 12);
        adst[0] = make_float4(red[0], red[1], red[2],  red[3]);
        adst[1] = make_float4(red[4], red[5], red[6],  red[7]);
        adst[2] = make_float4(red[8], red[9], red[10], red[11]);
    }
}

// ---------------- main: out[bs,v,i] = Rsum.bv + sum_p Rws.off + trans -------
__global__ __launch_bounds__(TB) void mesh_kernel(
    const float* __restrict__ rws,      // [256][64][12]
    const float* __restrict__ aux,      // [256][12]
    const float* __restrict__ offsets,  // [64][2562][3]
    const float* __restrict__ bverts,   // [2562][3]
    float* __restrict__ out)            // [256][2562][3]
{
    const int v   = blockIdx.x * TB + threadIdx.x;
    const int vc  = v < NV ? v : NV - 1;   // clamp loads, guard only the store
    const int bs0 = blockIdx.y * GROUP;

    const float bx = bverts[vc * 3 + 0];
    const float by = bverts[vc * 3 + 1];
    const float bz = bverts[vc * 3 + 2];

    float acc[GROUP][3];
#pragma unroll
    for (int g = 0; g < GROUP; ++g) {
        const float* a = aux + (size_t)(bs0 + g) * 12;   // wave-uniform -> s_load
        acc[g][0] = a[0] * bx + a[1] * by + a[2] * bz + a[9];
        acc[g][1] = a[3] * bx + a[4] * by + a[5] * bz + a[10];
        acc[g][2] = a[6] * bx + a[7] * by + a[8] * bz + a[11];
    }

    const float* rbase = rws + (size_t)bs0 * NP * RWS_STRIDE;

    // software pipeline: prefetch offsets for p+1 while doing FMAs for p
    const float* o0 = offsets + (size_t)vc * 3;
    float ox = o0[0], oy = o0[1], oz = o0[2];

#pragma unroll 2
    for (int p = 0; p < NP; ++p) {
        const int pn = (p + 1 < NP) ? (p + 1) : 0;       // branchless wraparound
        const float* on = offsets + ((size_t)pn * NV + vc) * 3;
        const float nox = on[0], noy = on[1], noz = on[2];

#pragma unroll
        for (int g = 0; g < GROUP; ++g) {
            const float* r = rbase + ((size_t)g * NP + p) * RWS_STRIDE;  // wave-uniform -> s_load
            acc[g][0] += r[0] * ox + r[1] * oy + r[2] * oz;
            acc[g][1] += r[3] * ox + r[4] * oy + r[5] * oz;
            acc[g][2] += r[6] * ox + r[7] * oy + r[8] * oz;
        }
        ox = nox; oy = noy; oz = noz;
    }

    if (v < NV) {
#pragma unroll
        for (int g = 0; g < GROUP; ++g) {
            float* po = out + ((size_t)(bs0 + g) * NV + v) * 3;
            __builtin_nontemporal_store(acc[g][0], po + 0);
            __builtin_nontemporal_store(acc[g][1], po + 1);
            __builtin_nontemporal_store(acc[g][2], po + 2);
        }
    }
}

extern "C" void kernel_launch(void* const* d_in, const int* in_sizes, int n_in,
                              void* d_out, int out_size, void* d_ws, size_t ws_size,
                              hipStream_t stream) {
    const float* scales     = (const float*)d_in[0];
    const float* transforms = (const float*)d_in[1];
    const float* weights    = (const float*)d_in[2];
    const float* offsets    = (const float*)d_in[3];
    const float* bverts     = (const float*)d_in[4];
    float* out = (float*)d_out;

    float* rws = (float*)d_ws;                             // 256*64*12 floats
    float* aux = rws + (size_t)BS_TOTAL * NP * RWS_STRIDE; // 256*12 floats

    prep_kernel<<<dim3(BS_TOTAL), dim3(64), 0, stream>>>(scales, transforms, weights, rws, aux);

    dim3 grid((NV + TB - 1) / TB, BS_TOTAL / GROUP);       // (21, 64) = 1344 blocks
    mesh_kernel<<<grid, dim3(TB), 0, stream>>>(rws, aux, offsets, bverts, out);
}

// Round 3
// 99.319 us; speedup vs baseline: 1.0886x; 1.0886x over previous
//
#include <hip/hip_runtime.h>

#define NP 64          // prototypes
#define NV 2562        // vertices
#define G  4           // bs per block
#define TB 128         // threads (2 waves)
#define VBLOCKS 21     // ceil(2562/128)
#define BSG 64         // 256/G bs-groups

// One fused kernel:
//  phase 1: 128 threads compute G*64 scaled rotation matrices -> LDS,
//           plus per-g reductions Rsum (sum_p Rws) and trans (sum_p w*t)
//  phase 2: thread = one vertex; p-loop with LDS-broadcast r and
//           2-deep prefetched offset loads.
__global__ __launch_bounds__(TB) void fused_kernel(
    const float* __restrict__ scales,      // [256]
    const float* __restrict__ transforms,  // [256][64][6]
    const float* __restrict__ weights,     // [256][64]
    const float* __restrict__ offsets,     // [64][2562][3]
    const float* __restrict__ bverts,      // [2562][3]
    float* __restrict__ out)               // [256][2562][3]
{
    __shared__ float srws[G][NP][12];      // 12 KiB
    __shared__ float saux[G][12];          // Rsum[9], trans[3]

    const int t   = threadIdx.x;
    const int bs0 = blockIdx.y * G;

    // ---------------- phase 1 ----------------
    {
        const int g    = t >> 5;           // 32 threads per g (half-wave)
        const int lane = t & 31;
        const int bs   = bs0 + g;
        const float sc = scales[bs];

        float red[12];
#pragma unroll
        for (int k = 0; k < 12; ++k) red[k] = 0.f;

#pragma unroll
        for (int k = 0; k < 2; ++k) {
            const int p = lane * 2 + k;
            const float* tr = transforms + ((size_t)bs * NP + p) * 6;
            const float tx = tr[0], ty = tr[1], tz = tr[2];
            const float ax = tr[3], ay = tr[4], az = tr[5];
            const float w  = weights[bs * NP + p];
            const float ws = w * sc;

            float sx, cx, sy, cy, szn, czn;
            __sincosf(ax, &sx, &cx);
            __sincosf(ay, &sy, &cy);
            __sincosf(az, &szn, &czn);

            float v12[12];
            v12[0] = (cy * czn) * ws;
            v12[1] = (-cy * szn) * ws;
            v12[2] = (sy) * ws;
            v12[3] = (cx * szn + sx * sy * czn) * ws;
            v12[4] = (cx * czn - sx * sy * szn) * ws;
            v12[5] = (-sx * cy) * ws;
            v12[6] = (sx * szn - cx * sy * czn) * ws;
            v12[7] = (sx * czn + cx * sy * szn) * ws;
            v12[8] = (cx * cy) * ws;
            v12[9]  = w * tx;
            v12[10] = w * ty;
            v12[11] = w * tz;

#pragma unroll
            for (int k2 = 0; k2 < 12; ++k2) {
                srws[g][p][k2] = v12[k2];
                red[k2] += v12[k2];
            }
        }
        // half-wave reduction (g occupies a contiguous 32-lane half)
#pragma unroll
        for (int m = 1; m < 32; m <<= 1) {
#pragma unroll
            for (int k = 0; k < 12; ++k) red[k] += __shfl_xor(red[k], m);
        }
        if (lane == 0) {
#pragma unroll
            for (int k = 0; k < 12; ++k) saux[g][k] = red[k];
        }
    }
    __syncthreads();

    // ---------------- phase 2 ----------------
    const int v  = blockIdx.x * TB + t;
    const int vc = v < NV ? v : NV - 1;    // clamp loads, guard store

    const float bx = bverts[vc * 3 + 0];
    const float by = bverts[vc * 3 + 1];
    const float bz = bverts[vc * 3 + 2];

    float acc[G][3];
#pragma unroll
    for (int g = 0; g < G; ++g) {
        const float* a = saux[g];
        acc[g][0] = a[0] * bx + a[1] * by + a[2] * bz + a[9];
        acc[g][1] = a[3] * bx + a[4] * by + a[5] * bz + a[10];
        acc[g][2] = a[6] * bx + a[7] * by + a[8] * bz + a[11];
    }

    // 2-deep software pipeline on the offset loads (~190 cyc cover)
    float ox[2], oy[2], oz[2];
#pragma unroll
    for (int k = 0; k < 2; ++k) {
        const float* o = offsets + ((size_t)k * NV + vc) * 3;
        ox[k] = o[0]; oy[k] = o[1]; oz[k] = o[2];
    }

#pragma unroll 2
    for (int p = 0; p < NP; ++p) {
        const int slot = p & 1;
        const float cox = ox[slot], coy = oy[slot], coz = oz[slot];

        const int pn = (p + 2 < NP) ? (p + 2) : p;   // harmless tail reload
        const float* on = offsets + ((size_t)pn * NV + vc) * 3;
        ox[slot] = on[0]; oy[slot] = on[1]; oz[slot] = on[2];

#pragma unroll
        for (int g = 0; g < G; ++g) {
            const float* r = srws[g][p];             // LDS broadcast
            acc[g][0] += r[0] * cox + r[1] * coy + r[2] * coz;
            acc[g][1] += r[3] * cox + r[4] * coy + r[5] * coz;
            acc[g][2] += r[6] * cox + r[7] * coy + r[8] * coz;
        }
    }

    if (v < NV) {
#pragma unroll
        for (int g = 0; g < G; ++g) {
            float* po = out + ((size_t)(bs0 + g) * NV + v) * 3;
            __builtin_nontemporal_store(acc[g][0], po + 0);
            __builtin_nontemporal_store(acc[g][1], po + 1);
            __builtin_nontemporal_store(acc[g][2], po + 2);
        }
    }
}

extern "C" void kernel_launch(void* const* d_in, const int* in_sizes, int n_in,
                              void* d_out, int out_size, void* d_ws, size_t ws_size,
                              hipStream_t stream) {
    const float* scales     = (const float*)d_in[0];
    const float* transforms = (const float*)d_in[1];
    const float* weights    = (const float*)d_in[2];
    const float* offsets    = (const float*)d_in[3];
    const float* bverts     = (const float*)d_in[4];
    float* out = (float*)d_out;

    dim3 grid(VBLOCKS, BSG);   // (21, 64) = 1344 blocks
    fused_kernel<<<grid, dim3(TB), 0, stream>>>(scales, transforms, weights,
                                                offsets, bverts, out);
}

// Round 4
// 87.817 us; speedup vs baseline: 1.2312x; 1.1310x over previous
//
#include <hip/hip_runtime.h>

#define NP 64
#define NV 2562
#define NVP 2576       // padded to 161*16
#define KK 192         // NP*3
#define NT 161         // n-tiles of 16
#define MQ 16          // m-quad blocks (64 m-tiles / 4 waves)

typedef short bf16x8 __attribute__((ext_vector_type(8)));   // 8 bf16 (4 VGPRs)
typedef float f32x4  __attribute__((ext_vector_type(4)));

// RNE float->bf16 (finite inputs)
static __device__ __forceinline__ unsigned short f2bf(float x) {
    unsigned u = __float_as_uint(x);
    return (unsigned short)((u + 0x7fffu + ((u >> 16) & 1u)) >> 16);
}

// ws layout (bytes):
//   A   : [1024][192] bf16  = 393216      (rows m=bs*4+i; i=3 rows unused garbage)
//   Bt  : [2576][192] bf16  = 989184      (Bt[v][p*3+j] = off[p][v][j]; v>=NV rows = 0)
//   aux : [256][12]  float  = 12288       (Rsum[9] row-major, trans[3])

// ---------------- prep_A: scaled rotation matrices -> bf16 A + aux ----------
__global__ __launch_bounds__(64) void prep_a_kernel(
    const float* __restrict__ scales,      // [256]
    const float* __restrict__ transforms,  // [256][64][6]
    const float* __restrict__ weights,     // [256][64]
    unsigned short* __restrict__ A,        // [1024][192] bf16 bits
    float* __restrict__ aux)               // [256][12]
{
    const int bs = blockIdx.x;
    const int p  = threadIdx.x;

    const float* t = transforms + ((size_t)bs * NP + p) * 6;
    const float tx = t[0], ty = t[1], tz = t[2];
    const float ax = t[3], ay = t[4], az = t[5];
    const float w  = weights[bs * NP + p];
    const float sc = scales[bs];
    const float ws = w * sc;

    float sx, cx, sy, cy, sz, cz;
    __sincosf(ax, &sx, &cx);
    __sincosf(ay, &sy, &cy);
    __sincosf(az, &sz, &cz);

    float v12[12];
    v12[0] = (cy * cz) * ws;
    v12[1] = (-cy * sz) * ws;
    v12[2] = (sy) * ws;
    v12[3] = (cx * sz + sx * sy * cz) * ws;
    v12[4] = (cx * cz - sx * sy * sz) * ws;
    v12[5] = (-sx * cy) * ws;
    v12[6] = (sx * sz - cx * sy * cz) * ws;
    v12[7] = (sx * cz + cx * sy * sz) * ws;
    v12[8] = (cx * cy) * ws;
    v12[9]  = w * tx;
    v12[10] = w * ty;
    v12[11] = w * tz;

    // A rows m = bs*4 + i, K-contiguous; element k = p*3 + j
#pragma unroll
    for (int i = 0; i < 3; ++i) {
        unsigned short* row = A + ((size_t)(bs * 4 + i)) * KK + p * 3;
        row[0] = f2bf(v12[i * 3 + 0]);
        row[1] = f2bf(v12[i * 3 + 1]);
        row[2] = f2bf(v12[i * 3 + 2]);
    }

    // wave reduction over p -> Rsum, trans (fp32 kept exact for epilogue)
    float red[12];
#pragma unroll
    for (int k = 0; k < 12; ++k) red[k] = v12[k];
#pragma unroll
    for (int m = 1; m < 64; m <<= 1) {
#pragma unroll
        for (int k = 0; k < 12; ++k) red[k] += __shfl_xor(red[k], m);
    }
    if (p == 0) {
#pragma unroll
        for (int k = 0; k < 12; ++k) aux[bs * 12 + k] = red[k];
    }
}

// ---------------- prep_B: transpose offsets -> bf16 Bt[v][k] ---------------
__global__ __launch_bounds__(128) void prep_b_kernel(
    const float* __restrict__ offsets,     // [64][2562][3]
    unsigned short* __restrict__ Bt)       // [2576][192]
{
    const int v = blockIdx.x * 128 + threadIdx.x;
    if (v >= NVP) return;
    const int p0 = blockIdx.y * 2;         // p-pair

    float o[6] = {0, 0, 0, 0, 0, 0};
    if (v < NV) {
        const float* a = offsets + ((size_t)p0 * NV + v) * 3;
        const float* b = offsets + ((size_t)(p0 + 1) * NV + v) * 3;
        o[0] = a[0]; o[1] = a[1]; o[2] = a[2];
        o[3] = b[0]; o[4] = b[1]; o[5] = b[2];
    }
    unsigned w0 = (unsigned)f2bf(o[0]) | ((unsigned)f2bf(o[1]) << 16);
    unsigned w1 = (unsigned)f2bf(o[2]) | ((unsigned)f2bf(o[3]) << 16);
    unsigned w2 = (unsigned)f2bf(o[4]) | ((unsigned)f2bf(o[5]) << 16);
    unsigned* dst = (unsigned*)(Bt + (size_t)v * KK + p0 * 3);  // 4B-aligned (12B steps)
    dst[0] = w0; dst[1] = w1; dst[2] = w2;
}

// ---------------- main: MFMA GEMM + fp32 epilogue ---------------------------
// grid (161, 16), 256 threads (4 waves). Wave w computes m-tile mt=by*4+w,
// n-tile nt=bx: D[16m x 16n] over K=192, then adds Rsum.bv + trans and stores.
__global__ __launch_bounds__(256) void gemm_kernel(
    const unsigned short* __restrict__ A,   // [1024][192] bf16
    const unsigned short* __restrict__ Bt,  // [2576][192] bf16
    const float* __restrict__ aux,          // [256][12]
    const float* __restrict__ bverts,       // [2562][3]
    float* __restrict__ out)                // [256][2562][3]
{
    __shared__ float tile[4][16][17];       // per-wave 16x16 + pad

    const int t    = threadIdx.x;
    const int wave = t >> 6;
    const int lane = t & 63;
    const int q    = lane >> 4;             // quad 0..3
    const int r16  = lane & 15;

    const int nt = blockIdx.x;
    const int mt = blockIdx.y * 4 + wave;
    const int n0 = nt * 16;

    const int am = mt * 16 + r16;           // A row this lane reads (m)
    const int bn = n0 + r16;                // Bt row this lane reads (n)

    const unsigned short* ap = A  + (size_t)am * KK + q * 8;
    const unsigned short* bp = Bt + (size_t)bn * KK + q * 8;

    f32x4 acc = {0.f, 0.f, 0.f, 0.f};
#pragma unroll
    for (int ks = 0; ks < 6; ++ks) {
        bf16x8 a = *(const bf16x8*)(ap + ks * 32);
        bf16x8 b = *(const bf16x8*)(bp + ks * 32);
        acc = __builtin_amdgcn_mfma_f32_16x16x32_bf16(a, b, acc, 0, 0, 0);
    }

    // D layout: col = lane&15 (n), row = q*4 + reg (m). Stash in LDS.
#pragma unroll
    for (int rg = 0; rg < 4; ++rg)
        tile[wave][q * 4 + rg][r16] = acc[rg];

    // epilogue: lanes 0..47 -> (vloc, i); store 192B contiguous per bs
    const int a_i  = lane % 3;
    const int vloc = lane / 3;
    const int v    = n0 + vloc;
    const int vc   = v < NV ? v : NV - 1;

    const float bx = bverts[vc * 3 + 0];
    const float by = bverts[vc * 3 + 1];
    const float bz = bverts[vc * 3 + 2];

    const int bs_base = mt * 4;
#pragma unroll
    for (int bi = 0; bi < 4; ++bi) {
        const int bs = bs_base + bi;
        const float* ax = aux + bs * 12;
        float val = tile[wave][bi * 4 + a_i][vloc];
        val += ax[a_i * 3 + 0] * bx + ax[a_i * 3 + 1] * by + ax[a_i * 3 + 2] * bz
             + ax[9 + a_i];
        if (lane < 48 && v < NV)
            out[(size_t)bs * NV * 3 + n0 * 3 + lane] = val;  // == (bs*NV+v)*3 + i
    }
}

extern "C" void kernel_launch(void* const* d_in, const int* in_sizes, int n_in,
                              void* d_out, int out_size, void* d_ws, size_t ws_size,
                              hipStream_t stream) {
    const float* scales     = (const float*)d_in[0];
    const float* transforms = (const float*)d_in[1];
    const float* weights    = (const float*)d_in[2];
    const float* offsets    = (const float*)d_in[3];
    const float* bverts     = (const float*)d_in[4];
    float* out = (float*)d_out;

    unsigned short* A  = (unsigned short*)d_ws;                 // 1024*192*2 B
    unsigned short* Bt = A + (size_t)1024 * KK;                 // 2576*192*2 B
    float* aux = (float*)(Bt + (size_t)NVP * KK);               // 256*12*4 B

    prep_a_kernel<<<dim3(256), dim3(64), 0, stream>>>(scales, transforms, weights, A, aux);
    prep_b_kernel<<<dim3((NVP + 127) / 128, NP / 2), dim3(128), 0, stream>>>(offsets, Bt);
    gemm_kernel<<<dim3(NT, MQ), dim3(256), 0, stream>>>(A, Bt, aux, bverts, out);
}